// Round 7
// baseline (99.468 us; speedup 1.0000x reference)
//
#include <hip/hip_runtime.h>
#include <math.h>

#define BATCH 8
#define DZ    32
#define NWH   48
#define NBOX  (NWH*NWH)          // 2304
#define KMAX  25
#define PIX   (384*384)          // 147456 per (k,b) slab
#define NTOT  (BATCH*NBOX)       // 18432
#define NW9   9
#define CHUNKS 4

typedef float vfloat4 __attribute__((ext_vector_type(4)));

__device__ __forceinline__ float sigm(float x) { return 1.0f / (1.0f + expf(-x)); }
// fast softplus: max(x,0) + ln(1+e^{-|x|}); abs err ~1e-6
__device__ __forceinline__ float sp_fast(float x) {
    return fmaxf(x, 0.0f) + __logf(1.0f + __expf(-fabsf(x)));
}

// ============ Kernel 1: conv1x1 + box decode (full grid, ~2us) ============
// ws planes: x1,y1,x2,y2,prob each [B*NBOX]
__global__ __launch_bounds__(256) void conv_kernel(
    const float* __restrict__ z, const float* __restrict__ wz, const float* __restrict__ bz,
    const float* __restrict__ lg, const float* __restrict__ wl, const float* __restrict__ bl,
    float* __restrict__ ws)
{
    int t = blockIdx.x * 256 + threadIdx.x;       // 8*576 = 4608 threads exactly
    int b = t / 576, j = t % 576;
    int iw = j / 12, ihq = j % 12;

    const float* zb = z  + (((size_t)b * DZ) * NWH + iw) * NWH + ihq * 4;
    const float* lb = lg + (((size_t)b * DZ) * NWH + iw) * NWH + ihq * 4;
    float b0 = bz[0], b1 = bz[1], b2 = bz[2], b3 = bz[3], blg = bl[0];
    vfloat4 a0 = {b0,b0,b0,b0}, a1 = {b1,b1,b1,b1}, a2 = {b2,b2,b2,b2},
            a3 = {b3,b3,b3,b3}, al = {blg,blg,blg,blg};
    #pragma unroll 8
    for (int d = 0; d < DZ; ++d) {
        vfloat4 zv = *(const vfloat4*)(zb + (size_t)d * NBOX);
        vfloat4 lv = *(const vfloat4*)(lb + (size_t)d * NBOX);
        float w0 = wz[d], w1 = wz[32+d], w2 = wz[64+d], w3 = wz[96+d], wv = wl[d];
        a0 += zv * w0; a1 += zv * w1; a2 += zv * w2; a3 += zv * w3; al += lv * wv;
    }

    float t0v[4] = {a0.x,a0.y,a0.z,a0.w};
    float t1v[4] = {a1.x,a1.y,a1.z,a1.w};
    float t2v[4] = {a2.x,a2.y,a2.z,a2.w};
    float t3v[4] = {a3.x,a3.y,a3.z,a3.w};
    float alv[4] = {al.x,al.y,al.z,al.w};
    float x1o[4], y1o[4], x2o[4], y2o[4], po[4];
    #pragma unroll
    for (int c = 0; c < 4; ++c) {
        float tx = sigm(t0v[c]), ty = sigm(t1v[c]), tw = sigm(t2v[c]), th = sigm(t3v[c]);
        float bx = 8.0f * ((float)iw + tx);
        float by = 8.0f * ((float)(ihq*4 + c) + ty);
        float bw = 12.0f + 36.0f * tw;
        float bh = 12.0f + 36.0f * th;
        x1o[c] = bx - 0.5f*bw;  y1o[c] = by - 0.5f*bh;
        x2o[c] = bx + 0.5f*bw;  y2o[c] = by + 0.5f*bh;
        po[c]  = sigm(alv[c]);
    }
    int o = b * NBOX + iw * NWH + ihq * 4;
    *(vfloat4*)(ws + 0*NTOT + o) = (vfloat4){x1o[0],x1o[1],x1o[2],x1o[3]};
    *(vfloat4*)(ws + 1*NTOT + o) = (vfloat4){y1o[0],y1o[1],y1o[2],y1o[3]};
    *(vfloat4*)(ws + 2*NTOT + o) = (vfloat4){x2o[0],x2o[1],x2o[2],x2o[3]};
    *(vfloat4*)(ws + 3*NTOT + o) = (vfloat4){y2o[0],y2o[1],y2o[2],y2o[3]};
    *(vfloat4*)(ws + 4*NTOT + o) = (vfloat4){po[0], po[1], po[2], po[3]};
}

// ============ Kernel 2: greedy NMS (8 blocks), boxes in registers ============
__global__ __launch_bounds__(576) void nms_kernel(const float* __restrict__ ws,
                                                  float* __restrict__ pfT)
{
    __shared__ vfloat4 boxS[NBOX];
    __shared__ float   prS[NBOX];
    __shared__ unsigned long long keyB[2][NW9];
    __shared__ int idxA[KMAX], okA[KMAX];

    const int b = blockIdx.x, t = threadIdx.x;
    const int n0 = t * 4;
    const int o  = b * NBOX + n0;

    vfloat4 X1 = *(const vfloat4*)(ws + 0*NTOT + o);
    vfloat4 Y1 = *(const vfloat4*)(ws + 1*NTOT + o);
    vfloat4 X2 = *(const vfloat4*)(ws + 2*NTOT + o);
    vfloat4 Y2 = *(const vfloat4*)(ws + 3*NTOT + o);
    vfloat4 P  = *(const vfloat4*)(ws + 4*NTOT + o);

    float x1r[4] = {X1.x,X1.y,X1.z,X1.w};
    float y1r[4] = {Y1.x,Y1.y,Y1.z,Y1.w};
    float x2r[4] = {X2.x,X2.y,X2.z,X2.w};
    float y2r[4] = {Y2.x,Y2.y,Y2.z,Y2.w};
    float pv [4] = {P.x, P.y, P.z, P.w};
    float arr[4], mkv[4];
    #pragma unroll
    for (int c = 0; c < 4; ++c) {
        arr[c] = (x2r[c]-x1r[c]) * (y2r[c]-y1r[c]);
        mkv[c] = (pv[c] > 0.1f) ? pv[c] : -INFINITY;
        boxS[n0+c] = (vfloat4){x1r[c], y1r[c], x2r[c], y2r[c]};
        prS [n0+c] = pv[c];
    }
    __syncthreads();

    float sx1=0.f, sy1=0.f, sx2=0.f, sy2=0.f, sar=0.f;
    for (int k = 0; k < KMAX; ++k) {
        unsigned long long best = 0ULL;
        #pragma unroll
        for (int c = 0; c < 4; ++c) {
            if (k > 0 && mkv[c] != -INFINITY) {
                float xi1 = fmaxf(sx1, x1r[c]);
                float yi1 = fmaxf(sy1, y1r[c]);
                float xi2 = fminf(sx2, x2r[c]);
                float yi2 = fminf(sy2, y2r[c]);
                float inter = fmaxf(xi2 - xi1, 0.f) * fmaxf(yi2 - yi1, 0.f);
                float uni   = sar + arr[c] - inter;
                float iou   = inter / fmaxf(uni, 1e-8f);
                if (iou > 0.3f) mkv[c] = -INFINITY;
            }
            if (mkv[c] != -INFINITY) {
                unsigned long long kk =
                    ((unsigned long long)__float_as_uint(mkv[c]) << 32) | (unsigned int)(~(n0+c));
                if (kk > best) best = kk;
            }
        }
        #pragma unroll
        for (int off = 32; off > 0; off >>= 1) {
            unsigned long long o2 = __shfl_down(best, off);
            if (o2 > best) best = o2;
        }
        if ((t & 63) == 0) keyB[k & 1][t >> 6] = best;
        __syncthreads();
        unsigned long long m = keyB[k & 1][0];
        #pragma unroll
        for (int w = 1; w < NW9; ++w) {
            unsigned long long o2 = keyB[k & 1][w];
            if (o2 > m) m = o2;
        }
        int sel = (m == 0ULL) ? 0 : (int)(~(unsigned int)(m & 0xFFFFFFFFULL));
        if (t == 0) { idxA[k] = sel; okA[k] = (m != 0ULL); }
        vfloat4 sb = boxS[sel];
        sx1 = sb.x; sy1 = sb.y; sx2 = sb.z; sy2 = sb.w;
        sar = (sx2 - sx1) * (sy2 - sy1);
    }

    if (t == 0) {
        #pragma unroll 1
        for (int k = 0; k < KMAX; ++k) {
            float mm = 0.f;
            for (int k2 = 0; k2 < KMAX; ++k2)
                if (idxA[k2] == idxA[k] && okA[k2]) mm = 1.f;
            pfT[b * 32 + k] = prS[idxA[k]] * mm;
        }
    }
}

// ============ Kernel 3: big streaming op — k over 4-lane groups, 4-chunk pipeline ============
// lane r = t&3 owns slabs {6r..6r+5} (+ slab 24 on r==0). Each block covers 256
// four-px columns in 4 chunks of 64; double-buffered register prefetch keeps 7
// loads in flight while computing/storing the previous chunk.
__global__ __launch_bounds__(256) void big_kernel(const float* __restrict__ wlg,
                                                  const float* __restrict__ pfT,
                                                  float* __restrict__ out)
{
    const size_t stride = (size_t)BATCH * PIX;
    const int t = threadIdx.x;
    const int r = t & 3;
    const int kb = 6 * r;
    const int b = blockIdx.x / 144;                       // 144 blocks per batch
    const size_t j0 = ((size_t)blockIdx.x * 256 + (t >> 2)) * 4;
    const float* pbase = wlg + (size_t)kb * stride;
    const float* p24   = wlg + (size_t)24 * stride;

    float pfv[7];
    #pragma unroll
    for (int s = 0; s < 6; ++s) pfv[s] = pfT[b * 32 + kb + s];
    pfv[6] = pfT[b * 32 + 24];

    vfloat4 buf[2][7];
    // prologue: chunk 0 loads
    #pragma unroll
    for (int s = 0; s < 6; ++s) buf[0][s] = *(const vfloat4*)(pbase + (size_t)s * stride + j0);
    if (r == 0) buf[0][6] = *(const vfloat4*)(p24 + j0);

    #pragma unroll
    for (int i = 0; i < CHUNKS; ++i) {
        const size_t j = j0 + (size_t)i * 256;            // 64 columns * 4 px
        if (i + 1 < CHUNKS) {
            const size_t jn = j + 256;
            #pragma unroll
            for (int s = 0; s < 6; ++s)
                buf[(i+1)&1][s] = *(const vfloat4*)(pbase + (size_t)s * stride + jn);
            if (r == 0) buf[(i+1)&1][6] = *(const vfloat4*)(p24 + jn);
        }

        // softplus in place; accumulate partial S
        vfloat4 acc = {0.f, 0.f, 0.f, 0.f};
        #pragma unroll
        for (int s = 0; s < 6; ++s) {
            vfloat4 v = buf[i&1][s];
            vfloat4 sv = { sp_fast(v.x), sp_fast(v.y), sp_fast(v.z), sp_fast(v.w) };
            buf[i&1][s] = sv;
            acc += sv;
        }
        vfloat4 sv6 = {0.f, 0.f, 0.f, 0.f};
        if (r == 0) {
            vfloat4 v = buf[i&1][6];
            sv6 = (vfloat4){ sp_fast(v.x), sp_fast(v.y), sp_fast(v.z), sp_fast(v.w) };
        }
        acc += sv6;

        // 4-lane butterfly: lanes {4q..4q+3} sum partial S
        #pragma unroll
        for (int mlane = 1; mlane <= 2; mlane <<= 1) {
            acc.x += __shfl_xor(acc.x, mlane);
            acc.y += __shfl_xor(acc.y, mlane);
            acc.z += __shfl_xor(acc.z, mlane);
            acc.w += __shfl_xor(acc.w, mlane);
        }

        // m = tanh(S)/max(S,1e-6); S>=0: tanh(S) = (1-e^{-2S})/(1+e^{-2S})
        vfloat4 m;
        {
            float ex = __expf(-2.f*acc.x), ey = __expf(-2.f*acc.y),
                  ez = __expf(-2.f*acc.z), ew = __expf(-2.f*acc.w);
            m.x = (1.f - ex) * __builtin_amdgcn_rcpf(1.f + ex) * __builtin_amdgcn_rcpf(fmaxf(acc.x, 1e-6f));
            m.y = (1.f - ey) * __builtin_amdgcn_rcpf(1.f + ey) * __builtin_amdgcn_rcpf(fmaxf(acc.y, 1e-6f));
            m.z = (1.f - ez) * __builtin_amdgcn_rcpf(1.f + ez) * __builtin_amdgcn_rcpf(fmaxf(acc.z, 1e-6f));
            m.w = (1.f - ew) * __builtin_amdgcn_rcpf(1.f + ew) * __builtin_amdgcn_rcpf(fmaxf(acc.w, 1e-6f));
        }

        float* ob = out + (size_t)kb * stride + j;
        #pragma unroll
        for (int s = 0; s < 6; ++s) {
            float c = pfv[s];
            vfloat4 sv = buf[i&1][s];
            vfloat4 o = { c * m.x * sv.x, c * m.y * sv.y, c * m.z * sv.z, c * m.w * sv.w };
            __builtin_nontemporal_store(o, (vfloat4*)(ob + (size_t)s * stride));
        }
        if (r == 0) {
            float c = pfv[6];
            vfloat4 o = { c * m.x * sv6.x, c * m.y * sv6.y, c * m.z * sv6.z, c * m.w * sv6.w };
            __builtin_nontemporal_store(o, (vfloat4*)(out + (size_t)24 * stride + j));
        }
    }
}

extern "C" void kernel_launch(void* const* d_in, const int* in_sizes, int n_in,
                              void* d_out, int out_size, void* d_ws, size_t ws_size,
                              hipStream_t stream)
{
    const float* zwhere = (const float*)d_in[0];
    const float* w_zw   = (const float*)d_in[1];
    const float* b_zw   = (const float*)d_in[2];
    const float* logit  = (const float*)d_in[3];
    const float* w_lg   = (const float*)d_in[4];
    const float* b_lg   = (const float*)d_in[5];
    const float* wlogit = (const float*)d_in[6];
    float* out = (float*)d_out;
    float* ws  = (float*)d_ws;
    float* pfT = ws + 5 * NTOT;                   // [BATCH][32] prob_few (transposed, padded)

    conv_kernel<<<(BATCH*576)/256, 256, 0, stream>>>(zwhere, w_zw, b_zw, logit, w_lg, b_lg, ws);
    nms_kernel<<<BATCH, 576, 0, stream>>>(ws, pfT);
    // 1152 blocks x 256 thr: each block = 256 four-px columns (4 chunks of 64), all 25 slabs
    big_kernel<<<(BATCH*PIX)/1024, 256, 0, stream>>>(wlogit, pfT, out);
}

// Round 8
// 97.501 us; speedup vs baseline: 1.0202x; 1.0202x over previous
//
#include <hip/hip_runtime.h>
#include <math.h>

#define BATCH 8
#define DZ    32
#define NWH   48
#define NBOX  (NWH*NWH)          // 2304
#define KMAX  25
#define PIX   (384*384)          // 147456 per (k,b) slab
#define NTOT  (BATCH*NBOX)       // 18432
#define NW9   9

typedef float vfloat4 __attribute__((ext_vector_type(4)));

__device__ __forceinline__ float sigm(float x) { return 1.0f / (1.0f + expf(-x)); }
// fast softplus: max(x,0) + ln(1+e^{-|x|}); abs err ~1e-6
__device__ __forceinline__ float sp_fast(float x) {
    return fmaxf(x, 0.0f) + __logf(1.0f + __expf(-fabsf(x)));
}

// ============ Kernel 1: conv1x1 + box decode (72 blocks x 64 thr) ============
// ws planes: x1,y1,x2,y2,prob each [B*NBOX]
__global__ __launch_bounds__(64) void conv_kernel(
    const float* __restrict__ z, const float* __restrict__ wz, const float* __restrict__ bz,
    const float* __restrict__ lg, const float* __restrict__ wl, const float* __restrict__ bl,
    float* __restrict__ ws)
{
    int t = blockIdx.x * 64 + threadIdx.x;        // 8*576 = 4608 threads exactly
    int b = t / 576, j = t % 576;
    int iw = j / 12, ihq = j % 12;

    const float* zb = z  + (((size_t)b * DZ) * NWH + iw) * NWH + ihq * 4;
    const float* lb = lg + (((size_t)b * DZ) * NWH + iw) * NWH + ihq * 4;
    float b0 = bz[0], b1 = bz[1], b2 = bz[2], b3 = bz[3], blg = bl[0];
    vfloat4 a0 = {b0,b0,b0,b0}, a1 = {b1,b1,b1,b1}, a2 = {b2,b2,b2,b2},
            a3 = {b3,b3,b3,b3}, al = {blg,blg,blg,blg};
    #pragma unroll 8
    for (int d = 0; d < DZ; ++d) {
        vfloat4 zv = *(const vfloat4*)(zb + (size_t)d * NBOX);
        vfloat4 lv = *(const vfloat4*)(lb + (size_t)d * NBOX);
        float w0 = wz[d], w1 = wz[32+d], w2 = wz[64+d], w3 = wz[96+d], wv = wl[d];
        a0 += zv * w0; a1 += zv * w1; a2 += zv * w2; a3 += zv * w3; al += lv * wv;
    }

    float t0v[4] = {a0.x,a0.y,a0.z,a0.w};
    float t1v[4] = {a1.x,a1.y,a1.z,a1.w};
    float t2v[4] = {a2.x,a2.y,a2.z,a2.w};
    float t3v[4] = {a3.x,a3.y,a3.z,a3.w};
    float alv[4] = {al.x,al.y,al.z,al.w};
    float x1o[4], y1o[4], x2o[4], y2o[4], po[4];
    #pragma unroll
    for (int c = 0; c < 4; ++c) {
        float tx = sigm(t0v[c]), ty = sigm(t1v[c]), tw = sigm(t2v[c]), th = sigm(t3v[c]);
        float bx = 8.0f * ((float)iw + tx);
        float by = 8.0f * ((float)(ihq*4 + c) + ty);
        float bw = 12.0f + 36.0f * tw;
        float bh = 12.0f + 36.0f * th;
        x1o[c] = bx - 0.5f*bw;  y1o[c] = by - 0.5f*bh;
        x2o[c] = bx + 0.5f*bw;  y2o[c] = by + 0.5f*bh;
        po[c]  = sigm(alv[c]);
    }
    int o = b * NBOX + iw * NWH + ihq * 4;
    *(vfloat4*)(ws + 0*NTOT + o) = (vfloat4){x1o[0],x1o[1],x1o[2],x1o[3]};
    *(vfloat4*)(ws + 1*NTOT + o) = (vfloat4){y1o[0],y1o[1],y1o[2],y1o[3]};
    *(vfloat4*)(ws + 2*NTOT + o) = (vfloat4){x2o[0],x2o[1],x2o[2],x2o[3]};
    *(vfloat4*)(ws + 3*NTOT + o) = (vfloat4){y2o[0],y2o[1],y2o[2],y2o[3]};
    *(vfloat4*)(ws + 4*NTOT + o) = (vfloat4){po[0], po[1], po[2], po[3]};
}

// ============ Kernel 2: greedy NMS (8 blocks), boxes in registers ============
__global__ __launch_bounds__(576) void nms_kernel(const float* __restrict__ ws,
                                                  float* __restrict__ pfT)
{
    __shared__ vfloat4 boxS[NBOX];
    __shared__ float   prS[NBOX];
    __shared__ unsigned long long keyB[2][NW9];
    __shared__ int idxA[KMAX], okA[KMAX];

    const int b = blockIdx.x, t = threadIdx.x;
    const int n0 = t * 4;
    const int o  = b * NBOX + n0;

    vfloat4 X1 = *(const vfloat4*)(ws + 0*NTOT + o);
    vfloat4 Y1 = *(const vfloat4*)(ws + 1*NTOT + o);
    vfloat4 X2 = *(const vfloat4*)(ws + 2*NTOT + o);
    vfloat4 Y2 = *(const vfloat4*)(ws + 3*NTOT + o);
    vfloat4 P  = *(const vfloat4*)(ws + 4*NTOT + o);

    float x1r[4] = {X1.x,X1.y,X1.z,X1.w};
    float y1r[4] = {Y1.x,Y1.y,Y1.z,Y1.w};
    float x2r[4] = {X2.x,X2.y,X2.z,X2.w};
    float y2r[4] = {Y2.x,Y2.y,Y2.z,Y2.w};
    float pv [4] = {P.x, P.y, P.z, P.w};
    float arr[4], mkv[4];
    #pragma unroll
    for (int c = 0; c < 4; ++c) {
        arr[c] = (x2r[c]-x1r[c]) * (y2r[c]-y1r[c]);
        mkv[c] = (pv[c] > 0.1f) ? pv[c] : -INFINITY;
        boxS[n0+c] = (vfloat4){x1r[c], y1r[c], x2r[c], y2r[c]};
        prS [n0+c] = pv[c];
    }
    __syncthreads();

    float sx1=0.f, sy1=0.f, sx2=0.f, sy2=0.f, sar=0.f;
    for (int k = 0; k < KMAX; ++k) {
        unsigned long long best = 0ULL;
        #pragma unroll
        for (int c = 0; c < 4; ++c) {
            if (k > 0 && mkv[c] != -INFINITY) {
                float xi1 = fmaxf(sx1, x1r[c]);
                float yi1 = fmaxf(sy1, y1r[c]);
                float xi2 = fminf(sx2, x2r[c]);
                float yi2 = fminf(sy2, y2r[c]);
                float inter = fmaxf(xi2 - xi1, 0.f) * fmaxf(yi2 - yi1, 0.f);
                float uni   = sar + arr[c] - inter;
                float iou   = inter / fmaxf(uni, 1e-8f);
                if (iou > 0.3f) mkv[c] = -INFINITY;
            }
            if (mkv[c] != -INFINITY) {
                unsigned long long kk =
                    ((unsigned long long)__float_as_uint(mkv[c]) << 32) | (unsigned int)(~(n0+c));
                if (kk > best) best = kk;
            }
        }
        #pragma unroll
        for (int off = 32; off > 0; off >>= 1) {
            unsigned long long o2 = __shfl_down(best, off);
            if (o2 > best) best = o2;
        }
        if ((t & 63) == 0) keyB[k & 1][t >> 6] = best;
        __syncthreads();
        unsigned long long m = keyB[k & 1][0];
        #pragma unroll
        for (int w = 1; w < NW9; ++w) {
            unsigned long long o2 = keyB[k & 1][w];
            if (o2 > m) m = o2;
        }
        int sel = (m == 0ULL) ? 0 : (int)(~(unsigned int)(m & 0xFFFFFFFFULL));
        if (t == 0) { idxA[k] = sel; okA[k] = (m != 0ULL); }
        vfloat4 sb = boxS[sel];
        sx1 = sb.x; sy1 = sb.y; sx2 = sb.z; sy2 = sb.w;
        sar = (sx2 - sx1) * (sy2 - sy1);
    }

    if (t == 0) {
        #pragma unroll 1
        for (int k = 0; k < KMAX; ++k) {
            float mm = 0.f;
            for (int k2 = 0; k2 < KMAX; ++k2)
                if (idxA[k2] == idxA[k] && okA[k2]) mm = 1.f;
            pfT[b * 32 + k] = prS[idxA[k]] * mm;
        }
    }
}

// ============ Kernel 3: big streaming op — k split across 4-lane groups ============
// Round-6 structure (best: 70.3us, 65% occ, VGPR 28). A/B change: PLAIN stores
// instead of __builtin_nontemporal_store — NT is the one constant across all
// ~70us-invariant variants; testing if the NT write path is the ceiling.
__global__ __launch_bounds__(256) void big_kernel(const float* __restrict__ wlg,
                                                  const float* __restrict__ pfT,
                                                  float* __restrict__ out)
{
    const size_t stride = (size_t)BATCH * PIX;
    const int t = threadIdx.x;
    const int r = t & 3;
    const size_t j = ((size_t)blockIdx.x * 64 + (t >> 2)) * 4;   // 4-px column
    const int b = (int)(blockIdx.x / 576);                       // block-uniform
    const int kb = 6 * r;
    const float* base = wlg + (size_t)kb * stride + j;

    vfloat4 acc = {0.f, 0.f, 0.f, 0.f};
    vfloat4 sp0, sp1, sp2, sp3, sp4, sp5;
#define LOADSP(s) { vfloat4 v = *(const vfloat4*)(base + (size_t)(s) * stride); \
    sp##s = (vfloat4){ sp_fast(v.x), sp_fast(v.y), sp_fast(v.z), sp_fast(v.w) }; \
    acc += sp##s; }
    LOADSP(0) LOADSP(1) LOADSP(2) LOADSP(3) LOADSP(4) LOADSP(5)
#undef LOADSP
    vfloat4 sp6 = {0.f, 0.f, 0.f, 0.f};
    if (r == 0) {
        vfloat4 v = *(const vfloat4*)(wlg + (size_t)24 * stride + j);
        sp6 = (vfloat4){ sp_fast(v.x), sp_fast(v.y), sp_fast(v.z), sp_fast(v.w) };
        acc += sp6;
    }

    // 4-lane butterfly: lanes {4q..4q+3} sum their partial S
    #pragma unroll
    for (int mlane = 1; mlane <= 2; mlane <<= 1) {
        acc.x += __shfl_xor(acc.x, mlane);
        acc.y += __shfl_xor(acc.y, mlane);
        acc.z += __shfl_xor(acc.z, mlane);
        acc.w += __shfl_xor(acc.w, mlane);
    }

    // m = tanh(S)/max(S,1e-6); S>=0:  tanh(S) = (1-e^{-2S})/(1+e^{-2S})
    vfloat4 m;
    {
        float ex = __expf(-2.f*acc.x), ey = __expf(-2.f*acc.y),
              ez = __expf(-2.f*acc.z), ew = __expf(-2.f*acc.w);
        m.x = (1.f - ex) * __builtin_amdgcn_rcpf(1.f + ex) * __builtin_amdgcn_rcpf(fmaxf(acc.x, 1e-6f));
        m.y = (1.f - ey) * __builtin_amdgcn_rcpf(1.f + ey) * __builtin_amdgcn_rcpf(fmaxf(acc.y, 1e-6f));
        m.z = (1.f - ez) * __builtin_amdgcn_rcpf(1.f + ez) * __builtin_amdgcn_rcpf(fmaxf(acc.z, 1e-6f));
        m.w = (1.f - ew) * __builtin_amdgcn_rcpf(1.f + ew) * __builtin_amdgcn_rcpf(fmaxf(acc.w, 1e-6f));
    }

    const float* pfb = pfT + b * 32 + kb;
    float* ob = out + (size_t)kb * stride + j;
#define STORE(s) { float c = pfb[s]; \
    vfloat4 o = { c * m.x * sp##s.x, c * m.y * sp##s.y, c * m.z * sp##s.z, c * m.w * sp##s.w }; \
    *(vfloat4*)(ob + (size_t)(s) * stride) = o; }
    STORE(0) STORE(1) STORE(2) STORE(3) STORE(4) STORE(5)
#undef STORE
    if (r == 0) {
        float c = pfT[b * 32 + 24];
        vfloat4 o = { c * m.x * sp6.x, c * m.y * sp6.y, c * m.z * sp6.z, c * m.w * sp6.w };
        *(vfloat4*)(out + (size_t)24 * stride + j) = o;
    }
}

extern "C" void kernel_launch(void* const* d_in, const int* in_sizes, int n_in,
                              void* d_out, int out_size, void* d_ws, size_t ws_size,
                              hipStream_t stream)
{
    const float* zwhere = (const float*)d_in[0];
    const float* w_zw   = (const float*)d_in[1];
    const float* b_zw   = (const float*)d_in[2];
    const float* logit  = (const float*)d_in[3];
    const float* w_lg   = (const float*)d_in[4];
    const float* b_lg   = (const float*)d_in[5];
    const float* wlogit = (const float*)d_in[6];
    float* out = (float*)d_out;
    float* ws  = (float*)d_ws;
    float* pfT = ws + 5 * NTOT;                   // [BATCH][32] prob_few (transposed, padded)

    conv_kernel<<<(BATCH*576)/64, 64, 0, stream>>>(zwhere, w_zw, b_zw, logit, w_lg, b_lg, ws);
    nms_kernel<<<BATCH, 576, 0, stream>>>(ws, pfT);
    // 4608 blocks: each covers 64 four-px columns x all 25 slabs (k split over lanes)
    big_kernel<<<(BATCH * PIX) / 256, 256, 0, stream>>>(wlogit, pfT, out);
}

// Round 9
// 96.764 us; speedup vs baseline: 1.0279x; 1.0076x over previous
//
#include <hip/hip_runtime.h>
#include <math.h>

#define BATCH 8
#define DZ    32
#define NWH   48
#define NBOX  (NWH*NWH)          // 2304
#define KMAX  25
#define PIX   (384*384)          // 147456 per (k,b) slab
#define NTOT  (BATCH*NBOX)       // 18432
#define NW9   9

typedef float vfloat4 __attribute__((ext_vector_type(4)));

__device__ __forceinline__ float sigm(float x) { return 1.0f / (1.0f + expf(-x)); }
// fast softplus: max(x,0) + ln(1+e^{-|x|}); abs err ~1e-6
__device__ __forceinline__ float sp_fast(float x) {
    return fmaxf(x, 0.0f) + __logf(1.0f + __expf(-fabsf(x)));
}

// ============ Kernel 1: conv1x1 + box decode (72 blocks x 64 thr) ============
__global__ __launch_bounds__(64) void conv_kernel(
    const float* __restrict__ z, const float* __restrict__ wz, const float* __restrict__ bz,
    const float* __restrict__ lg, const float* __restrict__ wl, const float* __restrict__ bl,
    float* __restrict__ ws)
{
    int t = blockIdx.x * 64 + threadIdx.x;        // 8*576 = 4608 threads exactly
    int b = t / 576, j = t % 576;
    int iw = j / 12, ihq = j % 12;

    const float* zb = z  + (((size_t)b * DZ) * NWH + iw) * NWH + ihq * 4;
    const float* lb = lg + (((size_t)b * DZ) * NWH + iw) * NWH + ihq * 4;
    float b0 = bz[0], b1 = bz[1], b2 = bz[2], b3 = bz[3], blg = bl[0];
    vfloat4 a0 = {b0,b0,b0,b0}, a1 = {b1,b1,b1,b1}, a2 = {b2,b2,b2,b2},
            a3 = {b3,b3,b3,b3}, al = {blg,blg,blg,blg};
    #pragma unroll 8
    for (int d = 0; d < DZ; ++d) {
        vfloat4 zv = *(const vfloat4*)(zb + (size_t)d * NBOX);
        vfloat4 lv = *(const vfloat4*)(lb + (size_t)d * NBOX);
        float w0 = wz[d], w1 = wz[32+d], w2 = wz[64+d], w3 = wz[96+d], wv = wl[d];
        a0 += zv * w0; a1 += zv * w1; a2 += zv * w2; a3 += zv * w3; al += lv * wv;
    }

    float t0v[4] = {a0.x,a0.y,a0.z,a0.w};
    float t1v[4] = {a1.x,a1.y,a1.z,a1.w};
    float t2v[4] = {a2.x,a2.y,a2.z,a2.w};
    float t3v[4] = {a3.x,a3.y,a3.z,a3.w};
    float alv[4] = {al.x,al.y,al.z,al.w};
    float x1o[4], y1o[4], x2o[4], y2o[4], po[4];
    #pragma unroll
    for (int c = 0; c < 4; ++c) {
        float tx = sigm(t0v[c]), ty = sigm(t1v[c]), tw = sigm(t2v[c]), th = sigm(t3v[c]);
        float bx = 8.0f * ((float)iw + tx);
        float by = 8.0f * ((float)(ihq*4 + c) + ty);
        float bw = 12.0f + 36.0f * tw;
        float bh = 12.0f + 36.0f * th;
        x1o[c] = bx - 0.5f*bw;  y1o[c] = by - 0.5f*bh;
        x2o[c] = bx + 0.5f*bw;  y2o[c] = by + 0.5f*bh;
        po[c]  = sigm(alv[c]);
    }
    int o = b * NBOX + iw * NWH + ihq * 4;
    *(vfloat4*)(ws + 0*NTOT + o) = (vfloat4){x1o[0],x1o[1],x1o[2],x1o[3]};
    *(vfloat4*)(ws + 1*NTOT + o) = (vfloat4){y1o[0],y1o[1],y1o[2],y1o[3]};
    *(vfloat4*)(ws + 2*NTOT + o) = (vfloat4){x2o[0],x2o[1],x2o[2],x2o[3]};
    *(vfloat4*)(ws + 3*NTOT + o) = (vfloat4){y2o[0],y2o[1],y2o[2],y2o[3]};
    *(vfloat4*)(ws + 4*NTOT + o) = (vfloat4){po[0], po[1], po[2], po[3]};
}

// ============ Kernel 2: greedy NMS (8 blocks), boxes in registers ============
__global__ __launch_bounds__(576) void nms_kernel(const float* __restrict__ ws,
                                                  float* __restrict__ pfT)
{
    __shared__ vfloat4 boxS[NBOX];
    __shared__ float   prS[NBOX];
    __shared__ unsigned long long keyB[2][NW9];
    __shared__ int idxA[KMAX], okA[KMAX];

    const int b = blockIdx.x, t = threadIdx.x;
    const int n0 = t * 4;
    const int o  = b * NBOX + n0;

    vfloat4 X1 = *(const vfloat4*)(ws + 0*NTOT + o);
    vfloat4 Y1 = *(const vfloat4*)(ws + 1*NTOT + o);
    vfloat4 X2 = *(const vfloat4*)(ws + 2*NTOT + o);
    vfloat4 Y2 = *(const vfloat4*)(ws + 3*NTOT + o);
    vfloat4 P  = *(const vfloat4*)(ws + 4*NTOT + o);

    float x1r[4] = {X1.x,X1.y,X1.z,X1.w};
    float y1r[4] = {Y1.x,Y1.y,Y1.z,Y1.w};
    float x2r[4] = {X2.x,X2.y,X2.z,X2.w};
    float y2r[4] = {Y2.x,Y2.y,Y2.z,Y2.w};
    float pv [4] = {P.x, P.y, P.z, P.w};
    float arr[4], mkv[4];
    #pragma unroll
    for (int c = 0; c < 4; ++c) {
        arr[c] = (x2r[c]-x1r[c]) * (y2r[c]-y1r[c]);
        mkv[c] = (pv[c] > 0.1f) ? pv[c] : -INFINITY;
        boxS[n0+c] = (vfloat4){x1r[c], y1r[c], x2r[c], y2r[c]};
        prS [n0+c] = pv[c];
    }
    __syncthreads();

    float sx1=0.f, sy1=0.f, sx2=0.f, sy2=0.f, sar=0.f;
    for (int k = 0; k < KMAX; ++k) {
        unsigned long long best = 0ULL;
        #pragma unroll
        for (int c = 0; c < 4; ++c) {
            if (k > 0 && mkv[c] != -INFINITY) {
                float xi1 = fmaxf(sx1, x1r[c]);
                float yi1 = fmaxf(sy1, y1r[c]);
                float xi2 = fminf(sx2, x2r[c]);
                float yi2 = fminf(sy2, y2r[c]);
                float inter = fmaxf(xi2 - xi1, 0.f) * fmaxf(yi2 - yi1, 0.f);
                float uni   = sar + arr[c] - inter;
                float iou   = inter / fmaxf(uni, 1e-8f);
                if (iou > 0.3f) mkv[c] = -INFINITY;
            }
            if (mkv[c] != -INFINITY) {
                unsigned long long kk =
                    ((unsigned long long)__float_as_uint(mkv[c]) << 32) | (unsigned int)(~(n0+c));
                if (kk > best) best = kk;
            }
        }
        #pragma unroll
        for (int off = 32; off > 0; off >>= 1) {
            unsigned long long o2 = __shfl_down(best, off);
            if (o2 > best) best = o2;
        }
        if ((t & 63) == 0) keyB[k & 1][t >> 6] = best;
        __syncthreads();
        unsigned long long m = keyB[k & 1][0];
        #pragma unroll
        for (int w = 1; w < NW9; ++w) {
            unsigned long long o2 = keyB[k & 1][w];
            if (o2 > m) m = o2;
        }
        int sel = (m == 0ULL) ? 0 : (int)(~(unsigned int)(m & 0xFFFFFFFFULL));
        if (t == 0) { idxA[k] = sel; okA[k] = (m != 0ULL); }
        vfloat4 sb = boxS[sel];
        sx1 = sb.x; sy1 = sb.y; sx2 = sb.z; sy2 = sb.w;
        sar = (sx2 - sx1) * (sy2 - sy1);
    }

    if (t == 0) {
        #pragma unroll 1
        for (int k = 0; k < KMAX; ++k) {
            float mm = 0.f;
            for (int k2 = 0; k2 < KMAX; ++k2)
                if (idxA[k2] == idxA[k] && okA[k2]) mm = 1.f;
            pfT[b * 32 + k] = prS[idxA[k]] * mm;
        }
    }
}

// ============ Kernel 3: big streaming op — k split across WAVES ============
// Block = 4 waves over the SAME 256-pixel tile; wave w owns slabs 6w..6w+5
// (wave 3 also owns slab 24). Every vmem instruction is a full-wave 1 KB
// CONTIGUOUS access within one slab (1 page/instr, vs 4-segment split in the
// lane-split layout). Partial S combined through 4 KB LDS + one barrier.
__global__ __launch_bounds__(256) void big_kernel(const float* __restrict__ wlg,
                                                  const float* __restrict__ pfT,
                                                  float* __restrict__ out)
{
    __shared__ vfloat4 accS[4][64];

    const size_t stride = (size_t)BATCH * PIX;
    const int t = threadIdx.x;
    const int w = t >> 6;                          // wave 0..3 (uniform per wave)
    const int l = t & 63;
    const int kb = 6 * w;                          // wave 3: slabs 18..24
    const size_t j = (size_t)blockIdx.x * 256 + (size_t)l * 4;
    const int b = blockIdx.x / 576;                // 576 blocks per batch
    const float* base = wlg + (size_t)kb * stride + j;

    vfloat4 acc = {0.f, 0.f, 0.f, 0.f};
    vfloat4 sp0, sp1, sp2, sp3, sp4, sp5;
#define LOADSP(s) { vfloat4 v = *(const vfloat4*)(base + (size_t)(s) * stride); \
    sp##s = (vfloat4){ sp_fast(v.x), sp_fast(v.y), sp_fast(v.z), sp_fast(v.w) }; \
    acc += sp##s; }
    LOADSP(0) LOADSP(1) LOADSP(2) LOADSP(3) LOADSP(4) LOADSP(5)
#undef LOADSP
    vfloat4 sp6 = {0.f, 0.f, 0.f, 0.f};
    if (w == 3) {                                  // wave-uniform branch
        vfloat4 v = *(const vfloat4*)(base + (size_t)6 * stride);
        sp6 = (vfloat4){ sp_fast(v.x), sp_fast(v.y), sp_fast(v.z), sp_fast(v.w) };
        acc += sp6;
    }

    accS[w][l] = acc;
    __syncthreads();
    vfloat4 S4 = accS[0][l] + accS[1][l] + accS[2][l] + accS[3][l];

    // m = tanh(S)/max(S,1e-6); S>=0:  tanh(S) = (1-e^{-2S})/(1+e^{-2S})
    vfloat4 m;
    {
        float ex = __expf(-2.f*S4.x), ey = __expf(-2.f*S4.y),
              ez = __expf(-2.f*S4.z), ew = __expf(-2.f*S4.w);
        m.x = (1.f - ex) * __builtin_amdgcn_rcpf(1.f + ex) * __builtin_amdgcn_rcpf(fmaxf(S4.x, 1e-6f));
        m.y = (1.f - ey) * __builtin_amdgcn_rcpf(1.f + ey) * __builtin_amdgcn_rcpf(fmaxf(S4.y, 1e-6f));
        m.z = (1.f - ez) * __builtin_amdgcn_rcpf(1.f + ez) * __builtin_amdgcn_rcpf(fmaxf(S4.z, 1e-6f));
        m.w = (1.f - ew) * __builtin_amdgcn_rcpf(1.f + ew) * __builtin_amdgcn_rcpf(fmaxf(S4.w, 1e-6f));
    }

    const float* pfb = pfT + b * 32 + kb;          // wave-uniform -> scalar loads
    float* ob = out + (size_t)kb * stride + j;
#define STORE(s) { float c = pfb[s]; \
    vfloat4 o = { c * m.x * sp##s.x, c * m.y * sp##s.y, c * m.z * sp##s.z, c * m.w * sp##s.w }; \
    *(vfloat4*)(ob + (size_t)(s) * stride) = o; }
    STORE(0) STORE(1) STORE(2) STORE(3) STORE(4) STORE(5)
#undef STORE
    if (w == 3) {
        float c = pfb[6];
        vfloat4 o = { c * m.x * sp6.x, c * m.y * sp6.y, c * m.z * sp6.z, c * m.w * sp6.w };
        *(vfloat4*)(ob + (size_t)6 * stride) = o;
    }
}

extern "C" void kernel_launch(void* const* d_in, const int* in_sizes, int n_in,
                              void* d_out, int out_size, void* d_ws, size_t ws_size,
                              hipStream_t stream)
{
    const float* zwhere = (const float*)d_in[0];
    const float* w_zw   = (const float*)d_in[1];
    const float* b_zw   = (const float*)d_in[2];
    const float* logit  = (const float*)d_in[3];
    const float* w_lg   = (const float*)d_in[4];
    const float* b_lg   = (const float*)d_in[5];
    const float* wlogit = (const float*)d_in[6];
    float* out = (float*)d_out;
    float* ws  = (float*)d_ws;
    float* pfT = ws + 5 * NTOT;                   // [BATCH][32] prob_few (transposed, padded)

    conv_kernel<<<(BATCH*576)/64, 64, 0, stream>>>(zwhere, w_zw, b_zw, logit, w_lg, b_lg, ws);
    nms_kernel<<<BATCH, 576, 0, stream>>>(ws, pfT);
    // 4608 blocks x 256 thr: block = 256-px tile, k split across 4 waves
    big_kernel<<<(BATCH * PIX) / 256, 256, 0, stream>>>(wlogit, pfT, out);
}

// Round 10
// 96.212 us; speedup vs baseline: 1.0338x; 1.0057x over previous
//
#include <hip/hip_runtime.h>
#include <hip/hip_fp16.h>
#include <math.h>

#define BATCH 8
#define DZ    32
#define NWH   48
#define NBOX  (NWH*NWH)          // 2304
#define KMAX  25
#define PIX   (384*384)          // 147456 per (k,b) slab
#define NTOT  (BATCH*NBOX)       // 18432
#define NW9   9

typedef float vfloat4 __attribute__((ext_vector_type(4)));

__device__ __forceinline__ float sigm(float x) { return 1.0f / (1.0f + expf(-x)); }
// fast softplus: max(x,0) + ln(1+e^{-|x|}); abs err ~1e-6
__device__ __forceinline__ float sp_fast(float x) {
    return fmaxf(x, 0.0f) + __logf(1.0f + __expf(-fabsf(x)));
}

// ============ Kernel 1: conv1x1 + box decode (72 blocks x 64 thr) ============
__global__ __launch_bounds__(64) void conv_kernel(
    const float* __restrict__ z, const float* __restrict__ wz, const float* __restrict__ bz,
    const float* __restrict__ lg, const float* __restrict__ wl, const float* __restrict__ bl,
    float* __restrict__ ws)
{
    int t = blockIdx.x * 64 + threadIdx.x;        // 8*576 = 4608 threads exactly
    int b = t / 576, j = t % 576;
    int iw = j / 12, ihq = j % 12;

    const float* zb = z  + (((size_t)b * DZ) * NWH + iw) * NWH + ihq * 4;
    const float* lb = lg + (((size_t)b * DZ) * NWH + iw) * NWH + ihq * 4;
    float b0 = bz[0], b1 = bz[1], b2 = bz[2], b3 = bz[3], blg = bl[0];
    vfloat4 a0 = {b0,b0,b0,b0}, a1 = {b1,b1,b1,b1}, a2 = {b2,b2,b2,b2},
            a3 = {b3,b3,b3,b3}, al = {blg,blg,blg,blg};
    #pragma unroll 8
    for (int d = 0; d < DZ; ++d) {
        vfloat4 zv = *(const vfloat4*)(zb + (size_t)d * NBOX);
        vfloat4 lv = *(const vfloat4*)(lb + (size_t)d * NBOX);
        float w0 = wz[d], w1 = wz[32+d], w2 = wz[64+d], w3 = wz[96+d], wv = wl[d];
        a0 += zv * w0; a1 += zv * w1; a2 += zv * w2; a3 += zv * w3; al += lv * wv;
    }

    float t0v[4] = {a0.x,a0.y,a0.z,a0.w};
    float t1v[4] = {a1.x,a1.y,a1.z,a1.w};
    float t2v[4] = {a2.x,a2.y,a2.z,a2.w};
    float t3v[4] = {a3.x,a3.y,a3.z,a3.w};
    float alv[4] = {al.x,al.y,al.z,al.w};
    float x1o[4], y1o[4], x2o[4], y2o[4], po[4];
    #pragma unroll
    for (int c = 0; c < 4; ++c) {
        float tx = sigm(t0v[c]), ty = sigm(t1v[c]), tw = sigm(t2v[c]), th = sigm(t3v[c]);
        float bx = 8.0f * ((float)iw + tx);
        float by = 8.0f * ((float)(ihq*4 + c) + ty);
        float bw = 12.0f + 36.0f * tw;
        float bh = 12.0f + 36.0f * th;
        x1o[c] = bx - 0.5f*bw;  y1o[c] = by - 0.5f*bh;
        x2o[c] = bx + 0.5f*bw;  y2o[c] = by + 0.5f*bh;
        po[c]  = sigm(alv[c]);
    }
    int o = b * NBOX + iw * NWH + ihq * 4;
    *(vfloat4*)(ws + 0*NTOT + o) = (vfloat4){x1o[0],x1o[1],x1o[2],x1o[3]};
    *(vfloat4*)(ws + 1*NTOT + o) = (vfloat4){y1o[0],y1o[1],y1o[2],y1o[3]};
    *(vfloat4*)(ws + 2*NTOT + o) = (vfloat4){x2o[0],x2o[1],x2o[2],x2o[3]};
    *(vfloat4*)(ws + 3*NTOT + o) = (vfloat4){y2o[0],y2o[1],y2o[2],y2o[3]};
    *(vfloat4*)(ws + 4*NTOT + o) = (vfloat4){po[0], po[1], po[2], po[3]};
}

// ============ Kernel 2: greedy NMS (8 blocks), boxes in registers ============
__global__ __launch_bounds__(576) void nms_kernel(const float* __restrict__ ws,
                                                  float* __restrict__ pfT)
{
    __shared__ vfloat4 boxS[NBOX];
    __shared__ float   prS[NBOX];
    __shared__ unsigned long long keyB[2][NW9];
    __shared__ int idxA[KMAX], okA[KMAX];

    const int b = blockIdx.x, t = threadIdx.x;
    const int n0 = t * 4;
    const int o  = b * NBOX + n0;

    vfloat4 X1 = *(const vfloat4*)(ws + 0*NTOT + o);
    vfloat4 Y1 = *(const vfloat4*)(ws + 1*NTOT + o);
    vfloat4 X2 = *(const vfloat4*)(ws + 2*NTOT + o);
    vfloat4 Y2 = *(const vfloat4*)(ws + 3*NTOT + o);
    vfloat4 P  = *(const vfloat4*)(ws + 4*NTOT + o);

    float x1r[4] = {X1.x,X1.y,X1.z,X1.w};
    float y1r[4] = {Y1.x,Y1.y,Y1.z,Y1.w};
    float x2r[4] = {X2.x,X2.y,X2.z,X2.w};
    float y2r[4] = {Y2.x,Y2.y,Y2.z,Y2.w};
    float pv [4] = {P.x, P.y, P.z, P.w};
    float arr[4], mkv[4];
    #pragma unroll
    for (int c = 0; c < 4; ++c) {
        arr[c] = (x2r[c]-x1r[c]) * (y2r[c]-y1r[c]);
        mkv[c] = (pv[c] > 0.1f) ? pv[c] : -INFINITY;
        boxS[n0+c] = (vfloat4){x1r[c], y1r[c], x2r[c], y2r[c]};
        prS [n0+c] = pv[c];
    }
    __syncthreads();

    float sx1=0.f, sy1=0.f, sx2=0.f, sy2=0.f, sar=0.f;
    for (int k = 0; k < KMAX; ++k) {
        unsigned long long best = 0ULL;
        #pragma unroll
        for (int c = 0; c < 4; ++c) {
            if (k > 0 && mkv[c] != -INFINITY) {
                float xi1 = fmaxf(sx1, x1r[c]);
                float yi1 = fmaxf(sy1, y1r[c]);
                float xi2 = fminf(sx2, x2r[c]);
                float yi2 = fminf(sy2, y2r[c]);
                float inter = fmaxf(xi2 - xi1, 0.f) * fmaxf(yi2 - yi1, 0.f);
                float uni   = sar + arr[c] - inter;
                float iou   = inter / fmaxf(uni, 1e-8f);
                if (iou > 0.3f) mkv[c] = -INFINITY;
            }
            if (mkv[c] != -INFINITY) {
                unsigned long long kk =
                    ((unsigned long long)__float_as_uint(mkv[c]) << 32) | (unsigned int)(~(n0+c));
                if (kk > best) best = kk;
            }
        }
        #pragma unroll
        for (int off = 32; off > 0; off >>= 1) {
            unsigned long long o2 = __shfl_down(best, off);
            if (o2 > best) best = o2;
        }
        if ((t & 63) == 0) keyB[k & 1][t >> 6] = best;
        __syncthreads();
        unsigned long long m = keyB[k & 1][0];
        #pragma unroll
        for (int w = 1; w < NW9; ++w) {
            unsigned long long o2 = keyB[k & 1][w];
            if (o2 > m) m = o2;
        }
        int sel = (m == 0ULL) ? 0 : (int)(~(unsigned int)(m & 0xFFFFFFFFULL));
        if (t == 0) { idxA[k] = sel; okA[k] = (m != 0ULL); }
        vfloat4 sb = boxS[sel];
        sx1 = sb.x; sy1 = sb.y; sx2 = sb.z; sy2 = sb.w;
        sar = (sx2 - sx1) * (sy2 - sy1);
    }

    if (t == 0) {
        #pragma unroll 1
        for (int k = 0; k < KMAX; ++k) {
            float mm = 0.f;
            for (int k2 = 0; k2 < KMAX; ++k2)
                if (idxA[k2] == idxA[k] && okA[k2]) mm = 1.f;
            pfT[b * 32 + k] = prS[idxA[k]] * mm;
        }
    }
}

// ============ Kernel 3: big streaming op — LDS as thread-private f16 sp store ============
// Block = 1024-px contiguous range. Phase 1: sweep k=0..24, per-slab 4 KB
// contiguous block-granule reads, softplus -> f16 pair-packed into LDS
// (thread-private slots: NO barriers, no sharing), accumulate S in 4 regs.
// Phase 2: sweep k again, LDS-read sp, scale, 4 KB contiguous stores.
// One active slab stream per block at a time (vs 7-50 fine-grained streams in
// all previous ~70us-invariant variants) -> DRAM row locality.
__global__ __launch_bounds__(256) void big_kernel(const float* __restrict__ wlg,
                                                  const float* __restrict__ pfT,
                                                  float* __restrict__ out)
{
    __shared__ uint2 spL[KMAX * 256];              // 25 x 256 x 8B = 51200 B (4 f16/thread/slab)

    const size_t stride = (size_t)BATCH * PIX;
    const int t = threadIdx.x;
    const size_t jb = (size_t)blockIdx.x * 1024 + (size_t)t * 4;
    const int b = blockIdx.x / 144;                // 144 blocks per batch (PIX/1024)
    const float* base = wlg + jb;

    vfloat4 S = {0.f, 0.f, 0.f, 0.f};
    #pragma unroll
    for (int k = 0; k < KMAX; ++k) {
        vfloat4 v = *(const vfloat4*)(base + (size_t)k * stride);
        float sx = sp_fast(v.x), sy = sp_fast(v.y), sz = sp_fast(v.z), sw = sp_fast(v.w);
        S.x += sx; S.y += sy; S.z += sz; S.w += sw;
        __half2 h01 = __floats2half2_rn(sx, sy);
        __half2 h23 = __floats2half2_rn(sz, sw);
        uint2 pk;
        pk.x = *(unsigned int*)&h01;
        pk.y = *(unsigned int*)&h23;
        spL[k * 256 + t] = pk;
    }

    // m = tanh(S)/max(S,1e-6); S>=0:  tanh(S) = (1-e^{-2S})/(1+e^{-2S})
    vfloat4 m;
    {
        float ex = __expf(-2.f*S.x), ey = __expf(-2.f*S.y),
              ez = __expf(-2.f*S.z), ew = __expf(-2.f*S.w);
        m.x = (1.f - ex) * __builtin_amdgcn_rcpf(1.f + ex) * __builtin_amdgcn_rcpf(fmaxf(S.x, 1e-6f));
        m.y = (1.f - ey) * __builtin_amdgcn_rcpf(1.f + ey) * __builtin_amdgcn_rcpf(fmaxf(S.y, 1e-6f));
        m.z = (1.f - ez) * __builtin_amdgcn_rcpf(1.f + ez) * __builtin_amdgcn_rcpf(fmaxf(S.z, 1e-6f));
        m.w = (1.f - ew) * __builtin_amdgcn_rcpf(1.f + ew) * __builtin_amdgcn_rcpf(fmaxf(S.w, 1e-6f));
    }

    const float* pfb = pfT + b * 32;               // block-uniform -> scalar loads
    float* ob = out + jb;
    #pragma unroll
    for (int k = 0; k < KMAX; ++k) {
        uint2 pk = spL[k * 256 + t];
        __half2 h01 = *(__half2*)&pk.x;
        __half2 h23 = *(__half2*)&pk.y;
        float2 a = __half22float2(h01);
        float2 d = __half22float2(h23);
        float c = pfb[k];
        vfloat4 o = { c * m.x * a.x, c * m.y * a.y, c * m.z * d.x, c * m.w * d.y };
        *(vfloat4*)(ob + (size_t)k * stride) = o;
    }
}

extern "C" void kernel_launch(void* const* d_in, const int* in_sizes, int n_in,
                              void* d_out, int out_size, void* d_ws, size_t ws_size,
                              hipStream_t stream)
{
    const float* zwhere = (const float*)d_in[0];
    const float* w_zw   = (const float*)d_in[1];
    const float* b_zw   = (const float*)d_in[2];
    const float* logit  = (const float*)d_in[3];
    const float* w_lg   = (const float*)d_in[4];
    const float* b_lg   = (const float*)d_in[5];
    const float* wlogit = (const float*)d_in[6];
    float* out = (float*)d_out;
    float* ws  = (float*)d_ws;
    float* pfT = ws + 5 * NTOT;                   // [BATCH][32] prob_few (transposed, padded)

    conv_kernel<<<(BATCH*576)/64, 64, 0, stream>>>(zwhere, w_zw, b_zw, logit, w_lg, b_lg, ws);
    nms_kernel<<<BATCH, 576, 0, stream>>>(ws, pfT);
    // 1152 blocks x 256 thr: block = 1024-px contiguous range, k swept sequentially
    big_kernel<<<(BATCH * PIX) / 1024, 256, 0, stream>>>(wlogit, pfT, out);
}